// Round 3
// baseline (384.851 us; speedup 1.0000x reference)
//
#include <hip/hip_runtime.h>

#define VN 50000
#define EN 800000

typedef short short8 __attribute__((ext_vector_type(8)));
typedef float float4v __attribute__((ext_vector_type(4)));

// ws layout in float units:
#define WS_FLAG 0        // int flag (1 = bf16 storage, 0 = f32 storage)
#define WS_KSF  16       // f32[4096]   K_self[o][i]
#define WS_GBF  4112     // f32[128]    gamma(64) ++ beta(64)
#define WS_WHI  4240     // ushort[20480] W hi-part, MFMA-B swizzled
#define WS_WLO  14480    // ushort[20480] W lo-part (residual), same swizzle
#define WS_ACC  24720    // f32[VN*64]  scatter accumulator

__device__ __forceinline__ float bf2f(unsigned short u) {
    return __uint_as_float(((unsigned int)u) << 16);
}
__device__ __forceinline__ unsigned short f2bf(float f) {
    unsigned int x = __float_as_uint(f);
    unsigned int r = (x + 0x7fffu + ((x >> 16) & 1u)) >> 16;  // RNE
    return (unsigned short)r;
}
__device__ __forceinline__ void rot4(float* f, float c, float s) {
#pragma unroll
    for (int p = 0; p < 4; ++p) {
        float u = f[2 * p], w = f[2 * p + 1];
        f[2 * p]     = c * u - s * w;
        f[2 * p + 1] = s * u + c * w;
    }
}

// ---------------------------------------------------------------------------
// Detect storage dtype of float tensors (bf16 vs f32) from bit patterns.
// ---------------------------------------------------------------------------
__global__ void detect_kernel(const unsigned short* __restrict__ xw,
                              int* __restrict__ flag) {
    int lane = threadIdx.x;                 // 64 threads
    unsigned short w = xw[2 * lane];
    int e = (w >> 7) & 0xFF;
    bool ok = (e >= 0x70 && e <= 0x85) || (w == 0);
    unsigned long long m = __ballot(ok);
    if (lane == 0) flag[0] = (__popcll(m) >= 40) ? 1 : 0;
}

// ---------------------------------------------------------------------------
// Canonicalize weights. W_neigh -> split bf16 hi/lo in MFMA-B fragment order:
//   Wswz[((slot*64)+ln)*8+j] = Wflat[k][n],  slot=ks*4+nt,
//   k=ks*32+(ln>>4)*8+j, n=nt*16+(ln&15), Wflat[b*64+i][o]=W_neigh[b][o][i]
// hi = bf16(w), lo = bf16(w - hi)  => hi+lo approximates w to ~2^-17.
// ---------------------------------------------------------------------------
__global__ __launch_bounds__(256) void convert_kernel(
    const void* __restrict__ Ks, const void* __restrict__ Wn,
    const void* __restrict__ gma, const void* __restrict__ bta,
    float* __restrict__ ws) {
    const int isbf = *((const int*)(ws + WS_FLAG));
    int idx = blockIdx.x * 256 + threadIdx.x;          // 0..24831 (need 24704)
    if (idx < 4096) {
        const float v = isbf ? bf2f(((const unsigned short*)Ks)[idx])
                             : ((const float*)Ks)[idx];
        ws[WS_KSF + idx] = v;
    } else if (idx < 4224) {
        int i = idx - 4096;
        const void* p = (i < 64) ? gma : bta;
        int j = i & 63;
        const float v = isbf ? bf2f(((const unsigned short*)p)[j])
                             : ((const float*)p)[j];
        ws[WS_GBF + i] = v;
    } else if (idx < 4224 + 20480) {
        int m = idx - 4224;
        int j = m & 7;
        int chunk = m >> 3;            // 0..2559
        int slot = chunk >> 6;         // 0..39
        int ln = chunk & 63;
        int ks = slot >> 2, nt = slot & 3;
        int k0 = ks * 32 + ((ln >> 4) * 8);
        int b = k0 >> 6;
        int i = (k0 & 63) + j;
        int n = nt * 16 + (ln & 15);
        int src = (b * 64 + n) * 64 + i;
        float wv = isbf ? bf2f(((const unsigned short*)Wn)[src])
                        : ((const float*)Wn)[src];
        unsigned short hi = f2bf(wv);
        unsigned short lo = f2bf(wv - bf2f(hi));
        ((unsigned short*)(ws + WS_WHI))[m] = hi;
        ((unsigned short*)(ws + WS_WLO))[m] = lo;
    }
}

// ---------------------------------------------------------------------------
// Edge kernel: 512 threads = 8 waves, 16 edges/wave -> 128 edges/block.
// msg(E x 64) = U(E x 320) * Wflat(320 x 64), U[e,b*64+i]=basis[e,b]*fq[e,i].
// Precision: split-bf16 3-term MFMA  u*w = uhi*whi + ulo*whi + uhi*wlo
// (f32-grade accuracy; plain bf16 fails the near-zero-norm softplus gate).
// Two LDS phases (Whi then Wlo) keep LDS at 40KB -> 4 blocks/CU.
// ---------------------------------------------------------------------------
__global__ __launch_bounds__(512) void edge_kernel(
    const void* __restrict__ xv,
    const int* __restrict__ eidx,          // (2,E)
    const void* __restrict__ angv,
    const void* __restrict__ trpv,
    const float* __restrict__ ws) {
    __shared__ unsigned short Blds[40 * 512];   // 40KB, staged hi then lo

    const int isbf = *((const int*)(ws + WS_FLAG));
    const unsigned short* Whi = (const unsigned short*)(ws + WS_WHI);
    const unsigned short* Wlo = (const unsigned short*)(ws + WS_WLO);
    float* acc = (float*)(ws + WS_ACC);

    const int t = threadIdx.x;
    const int lane = t & 63;
    const int w = t >> 6;                  // 0..7

    // ---- stage B hi: 2560 16B chunks, 5 per thread ------------------------
#pragma unroll
    for (int r = 0; r < 5; ++r) {
        int chunk = r * 512 + t;
        ((uint4*)Blds)[chunk] = ((const uint4*)Whi)[chunk];
    }

    // ---- per-lane A data: edge m = lane&15, quad q = lane>>4 --------------
    const int q = lane >> 4;
    const int e = blockIdx.x * 128 + w * 16 + (lane & 15);
    const int s = eidx[e];

    float fA[8], fB[8];
    if (isbf) {
        const unsigned short* xs = (const unsigned short*)xv;
#pragma unroll
        for (int j = 0; j < 8; ++j) {
            fA[j] = bf2f(xs[(size_t)s * 64 + q * 8 + j]);
            fB[j] = bf2f(xs[(size_t)s * 64 + 32 + q * 8 + j]);
        }
    } else {
        const float* xf = (const float*)xv;
        float4v a0 = *(const float4v*)(xf + (size_t)s * 64 + q * 8);
        float4v a1 = *(const float4v*)(xf + (size_t)s * 64 + q * 8 + 4);
        float4v b0 = *(const float4v*)(xf + (size_t)s * 64 + 32 + q * 8);
        float4v b1 = *(const float4v*)(xf + (size_t)s * 64 + 32 + q * 8 + 4);
#pragma unroll
        for (int j = 0; j < 4; ++j) {
            fA[j] = a0[j]; fA[4 + j] = a1[j];
            fB[j] = b0[j]; fB[4 + j] = b1[j];
        }
    }

    // transport: ch0..15 order0, ch16..47 order1 (phi), ch48..63 order2 (2phi)
    {
        float tphi = isbf ? bf2f(((const unsigned short*)trpv)[e])
                          : ((const float*)trpv)[e];
        float ct = cosf(tphi), st = sinf(tphi);
        float ct2 = ct * ct - st * st, st2 = 2.f * ct * st;
        if (q >= 2) rot4(fA, ct, st);      // segA q>=2 -> ch16..31, order1
        if (q < 2)  rot4(fB, ct, st);      // segB q<2  -> ch32..47, order1
        else        rot4(fB, ct2, st2);    // segB q>=2 -> ch48..63, order2
    }

    float basis[5];
    {
        float aphi = isbf ? bf2f(((const unsigned short*)angv)[e])
                          : ((const float*)angv)[e];
        float ca = cosf(aphi), sa = sinf(aphi);
        basis[0] = 1.f; basis[1] = ca; basis[2] = sa;
        basis[3] = ca * ca - sa * sa; basis[4] = 2.f * ca * sa;
    }

    __syncthreads();

    // ---- pass 1: (uhi + ulo) * Whi ---------------------------------------
    float4v accv[4];
#pragma unroll
    for (int nt = 0; nt < 4; ++nt) accv[nt] = (float4v){0.f, 0.f, 0.f, 0.f};

#pragma unroll
    for (int ks = 0; ks < 10; ++ks) {
        const float bs = basis[ks >> 1];
        const float* sg = (ks & 1) ? fB : fA;
        short8 hi, lo;
#pragma unroll
        for (int j = 0; j < 8; ++j) {
            float v = bs * sg[j];
            unsigned short h = f2bf(v);
            hi[j] = (short)h;
            lo[j] = (short)f2bf(v - bf2f(h));
        }
#pragma unroll
        for (int nt = 0; nt < 4; ++nt) {
            short8 bfr = *reinterpret_cast<const short8*>(
                &Blds[(ks * 4 + nt) * 512 + lane * 8]);
            accv[nt] = __builtin_amdgcn_mfma_f32_16x16x32_bf16(hi, bfr, accv[nt], 0, 0, 0);
            accv[nt] = __builtin_amdgcn_mfma_f32_16x16x32_bf16(lo, bfr, accv[nt], 0, 0, 0);
        }
    }

    __syncthreads();   // all waves done reading Whi
#pragma unroll
    for (int r = 0; r < 5; ++r) {
        int chunk = r * 512 + t;
        ((uint4*)Blds)[chunk] = ((const uint4*)Wlo)[chunk];
    }
    __syncthreads();

    // ---- pass 2: uhi * Wlo ------------------------------------------------
#pragma unroll
    for (int ks = 0; ks < 10; ++ks) {
        const float bs = basis[ks >> 1];
        const float* sg = (ks & 1) ? fB : fA;
        short8 hi;
#pragma unroll
        for (int j = 0; j < 8; ++j) hi[j] = (short)f2bf(bs * sg[j]);
#pragma unroll
        for (int nt = 0; nt < 4; ++nt) {
            short8 bfr = *reinterpret_cast<const short8*>(
                &Blds[(ks * 4 + nt) * 512 + lane * 8]);
            accv[nt] = __builtin_amdgcn_mfma_f32_16x16x32_bf16(hi, bfr, accv[nt], 0, 0, 0);
        }
    }

    // ---- scatter: C/D layout col=lane&15 (out ch), row=(lane>>4)*4+reg ----
    const int col = lane & 15;
#pragma unroll
    for (int reg = 0; reg < 4; ++reg) {
        int erow = blockIdx.x * 128 + w * 16 + q * 4 + reg;
        int tg = eidx[EN + erow];
        float* dst = acc + (size_t)tg * 64 + col;
#pragma unroll
        for (int nt = 0; nt < 4; ++nt)
            atomicAdd(dst + nt * 16, accv[nt][reg]);
    }
}

// ---------------------------------------------------------------------------
// Node kernel: wave per node (lane = channel).
// out = K_self @ x[v] + acc[v]; LN; relu/softplus-gate; + x[v]
// ---------------------------------------------------------------------------
__global__ __launch_bounds__(256) void node_kernel(
    const void* __restrict__ xv,
    const float* __restrict__ ws,
    void* __restrict__ outv) {
    __shared__ float Klds[64 * 64];   // Klds[i*64+o] = K_self[o][i]
    __shared__ float xrow[4][64];

    const int isbf = *((const int*)(ws + WS_FLAG));
    const float* Ksf = ws + WS_KSF;
    const float* gbf = ws + WS_GBF;
    const float* acc = ws + WS_ACC;

    const int t = threadIdx.x;
#pragma unroll
    for (int r = 0; r < 16; ++r) {
        int idx = r * 256 + t;
        int o = idx >> 6, i = idx & 63;
        Klds[i * 64 + o] = Ksf[o * 64 + i];
    }
    __syncthreads();

    const int w = t >> 6, lane = t & 63;
    const int v = blockIdx.x * 4 + w;   // V = 12500*4 exact

    float xval = isbf ? bf2f(((const unsigned short*)xv)[(size_t)v * 64 + lane])
                      : ((const float*)xv)[(size_t)v * 64 + lane];
    xrow[w][lane] = xval;   // same-wave LDS write->read: HW-ordered per wave

    float s = acc[(size_t)v * 64 + lane];
#pragma unroll
    for (int i = 0; i < 64; ++i)
        s = fmaf(Klds[i * 64 + lane], xrow[w][i], s);

    // LN over 64 lanes
    float s1 = s, s2 = s * s;
#pragma unroll
    for (int off = 32; off > 0; off >>= 1) {
        s1 += __shfl_xor(s1, off, 64);
        s2 += __shfl_xor(s2, off, 64);
    }
    float mu = s1 * (1.f / 64.f);
    float var = s2 * (1.f / 64.f) - mu * mu;
    float h = (s - mu) * rsqrtf(var + 1e-5f) * gbf[lane] + gbf[64 + lane];

    // nonlinearity: ch<16 relu; else norm-gated softplus on (even,odd) pairs
    float prt = __shfl_xor(h, 1, 64);
    float rlt;
    if (lane < 16) {
        rlt = fmaxf(h, 0.f);
    } else {
        float nrm = sqrtf(h * h + prt * prt);
        nrm = fmaxf(nrm, 1e-8f);
        float sp = (nrm > 20.f) ? nrm : log1pf(__expf(nrm));
        rlt = h * (sp / nrm);
    }
    float r = rlt + xval;
    if (isbf) ((unsigned short*)outv)[(size_t)v * 64 + lane] = f2bf(r);
    else      ((float*)outv)[(size_t)v * 64 + lane] = r;
}

extern "C" void kernel_launch(void* const* d_in, const int* in_sizes, int n_in,
                              void* d_out, int out_size, void* d_ws, size_t ws_size,
                              hipStream_t stream) {
    const void* x   = d_in[0];
    const int* eidx = (const int*)d_in[1];
    const void* ang = d_in[2];
    const void* trp = d_in[3];
    const void* Ks  = d_in[4];
    const void* Wn  = d_in[5];
    const void* gma = d_in[6];
    const void* bta = d_in[7];
    float* ws = (float*)d_ws;

    hipMemsetAsync(ws + WS_ACC, 0, (size_t)VN * 64 * sizeof(float), stream);
    detect_kernel<<<1, 64, 0, stream>>>((const unsigned short*)x, (int*)ws);
    convert_kernel<<<97, 256, 0, stream>>>(Ks, Wn, gma, bta, ws);
    edge_kernel<<<EN / 128, 512, 0, stream>>>(x, eidx, ang, trp, ws);
    node_kernel<<<VN / 4, 256, 0, stream>>>(x, ws, d_out);
}